// Round 7
// baseline (464.844 us; speedup 1.0000x reference)
//
#include <hip/hip_runtime.h>

#define NN 100000
#define NE 1600000
#define F 128
#define CAP 64

// ---------------- build inverted adjacency (fixed-capacity buckets) ----------
__global__ __launch_bounds__(256) void build_k(const int* __restrict__ erow,
                                               const int* __restrict__ ecol,
                                               int* __restrict__ cnt,
                                               int* __restrict__ bucket) {
    int e = blockIdx.x * 256 + threadIdx.x;
    if (e >= NE) return;
    int r = erow[e];
    int pos = atomicAdd(&cnt[r], 1);
    if (pos < CAP) bucket[r * CAP + pos] = ecol[e];
}

// ---- fp32 GEMM v4: h = x@W + b. 512 thr, 256x128 tile, 8x8/thread. ----------
// sW 64KB -> 2 blocks/CU -> 4 waves/SIMD; A streamed (16-lane broadcast).
__global__ __launch_bounds__(512, 4) void gemm_h(const float* __restrict__ A,
                                                 const float* __restrict__ W,
                                                 const float* __restrict__ b,
                                                 float* __restrict__ h) {
    __shared__ float sW[128 * 128];   // 64 KB
    const int tid = threadIdx.x;
    const int base = blockIdx.x * 256;

    // stage W (128x128): 512 threads x 8 float4
    #pragma unroll
    for (int i = 0; i < 8; ++i) {
        int idx = tid + i * 512;
        int r = idx >> 5, c4 = idx & 31;
        *(float4*)&sW[r * 128 + c4 * 4] = *(const float4*)(W + r * F + c4 * 4);
    }
    __syncthreads();

    const int tc = tid & 15;   // cols tc*8 .. tc*8+7
    const int tr = tid >> 4;   // 0..31: rows tr + 32*i, i=0..7

    const float* arow[8];
    #pragma unroll
    for (int i = 0; i < 8; ++i) {
        int row = base + tr + 32 * i;
        int rowc = row < NN ? row : NN - 1;   // clamp; store masked
        arow[i] = A + (size_t)rowc * F;
    }

    float acc[8][8];
    #pragma unroll
    for (int i = 0; i < 8; ++i)
        #pragma unroll
        for (int j = 0; j < 8; ++j) acc[i][j] = 0.f;

    for (int k4 = 0; k4 < 32; ++k4) {
        float4 a4[8];
        #pragma unroll
        for (int i = 0; i < 8; ++i)
            a4[i] = *(const float4*)(arow[i] + k4 * 4);   // 8 loads in flight
        #pragma unroll
        for (int kk = 0; kk < 4; ++kk) {
            int k = k4 * 4 + kk;
            float4 w0 = *(const float4*)&sW[k * 128 + tc * 8];
            float4 w1 = *(const float4*)&sW[k * 128 + tc * 8 + 4];
            float w[8] = {w0.x, w0.y, w0.z, w0.w, w1.x, w1.y, w1.z, w1.w};
            #pragma unroll
            for (int i = 0; i < 8; ++i) {
                const float* ap = (const float*)&a4[i];   // kk unrolled: static idx
                float av = ap[kk];
                #pragma unroll
                for (int j = 0; j < 8; ++j)
                    acc[i][j] = fmaf(av, w[j], acc[i][j]);
            }
        }
    }

    // epilogue: + bias, store h (no norm here — norm happens after aggregation)
    float4 b0 = *(const float4*)(b + tc * 8);
    float4 b1 = *(const float4*)(b + tc * 8 + 4);
    float bb[8] = {b0.x, b0.y, b0.z, b0.w, b1.x, b1.y, b1.z, b1.w};
    #pragma unroll
    for (int i = 0; i < 8; ++i) {
        int row = base + tr + 32 * i;
        if (row < NN) {
            float4 o0 = make_float4(acc[i][0] + bb[0], acc[i][1] + bb[1],
                                    acc[i][2] + bb[2], acc[i][3] + bb[3]);
            float4 o1 = make_float4(acc[i][4] + bb[4], acc[i][5] + bb[5],
                                    acc[i][6] + bb[6], acc[i][7] + bb[7]);
            *(float4*)(h + (size_t)row * F + tc * 8) = o0;
            *(float4*)(h + (size_t)row * F + tc * 8 + 4) = o1;
        }
    }
}

// ------ mean aggregation over h + fused deg-divide + L2-normalize ------------
// 32 lanes per node, float4 gathers; deg==0 rows come out exactly 0.
__global__ __launch_bounds__(256) void agg_k(const float* __restrict__ h,
                                             const int* __restrict__ cnt,
                                             const int* __restrict__ bucket,
                                             float* __restrict__ out) {
    const int grp  = threadIdx.x >> 5;
    const int node = blockIdx.x * 8 + grp;
    const int gl   = threadIdx.x & 31;
    if (node >= NN) return;
    const int c = cnt[node];
    const int m = c < CAP ? c : CAP;
    const int idx0 = (gl < m)      ? bucket[node * CAP + gl]      : 0;
    const int idx1 = (32 + gl < m) ? bucket[node * CAP + 32 + gl] : 0;

    float sx = 0.f, sy = 0.f, sz = 0.f, sw = 0.f;
    int k = 0;
    for (; k + 4 <= m; k += 4) {
        int i0 = __shfl((k + 0) < 32 ? idx0 : idx1, (k + 0) & 31, 32);
        int i1 = __shfl((k + 1) < 32 ? idx0 : idx1, (k + 1) & 31, 32);
        int i2 = __shfl((k + 2) < 32 ? idx0 : idx1, (k + 2) & 31, 32);
        int i3 = __shfl((k + 3) < 32 ? idx0 : idx1, (k + 3) & 31, 32);
        float4 v0 = *(const float4*)(h + (size_t)i0 * F + gl * 4);
        float4 v1 = *(const float4*)(h + (size_t)i1 * F + gl * 4);
        float4 v2 = *(const float4*)(h + (size_t)i2 * F + gl * 4);
        float4 v3 = *(const float4*)(h + (size_t)i3 * F + gl * 4);
        sx += v0.x + v1.x + v2.x + v3.x;
        sy += v0.y + v1.y + v2.y + v3.y;
        sz += v0.z + v1.z + v2.z + v3.z;
        sw += v0.w + v1.w + v2.w + v3.w;
    }
    for (; k < m; ++k) {
        int ii = __shfl(k < 32 ? idx0 : idx1, k & 31, 32);
        float4 v = *(const float4*)(h + (size_t)ii * F + gl * 4);
        sx += v.x; sy += v.y; sz += v.z; sw += v.w;
    }
    const float inv = 1.f / (float)(c > 1 ? c : 1);
    float vx = sx * inv, vy = sy * inv, vz = sz * inv, vw = sw * inv;

    float sumsq = vx * vx + vy * vy + vz * vz + vw * vw;
    #pragma unroll
    for (int off = 1; off < 32; off <<= 1)
        sumsq += __shfl_xor(sumsq, off, 32);
    float s = 1.f / fmaxf(sqrtf(sumsq), 1e-12f);

    float4 r;
    r.x = vx * s; r.y = vy * s; r.z = vz * s; r.w = vw * s;
    *(float4*)(out + (size_t)node * F + gl * 4) = r;
}

extern "C" void kernel_launch(void* const* d_in, const int* in_sizes, int n_in,
                              void* d_out, int out_size, void* d_ws, size_t ws_size,
                              hipStream_t stream) {
    const float* x    = (const float*)d_in[0];
    const int*   erow = (const int*)d_in[1];
    const int*   ecol = (const int*)d_in[2];
    const float* W    = (const float*)d_in[3];
    const float* b    = (const float*)d_in[4];
    float* out = (float*)d_out;

    // workspace layout: h [NN*F f32] | cnt [NN i32] | bucket [NN*CAP i32]
    float* h      = (float*)d_ws;
    int*   cnt    = (int*)(h + (size_t)NN * F);
    int*   bucket = cnt + NN;

    hipMemsetAsync(cnt, 0, NN * sizeof(int), stream);
    build_k<<<(NE + 255) / 256, 256, 0, stream>>>(erow, ecol, cnt, bucket);
    gemm_h<<<(NN + 255) / 256, 512, 0, stream>>>(x, W, b, h);
    agg_k<<<(NN + 7) / 8, 256, 0, stream>>>(h, cnt, bucket, out);
}

// Round 11
// 382.088 us; speedup vs baseline: 1.2166x; 1.2166x over previous
//
#include <hip/hip_runtime.h>

#define NN 100000
#define NE 1600000
#define F 128
#define CAP 64

// ---------------- build inverted adjacency (fixed-capacity buckets) ----------
__global__ __launch_bounds__(256) void build_k(const int* __restrict__ erow,
                                               const int* __restrict__ ecol,
                                               int* __restrict__ cnt,
                                               int* __restrict__ bucket) {
    int e = blockIdx.x * 256 + threadIdx.x;
    if (e >= NE) return;
    int r = erow[e];
    int pos = atomicAdd(&cnt[r], 1);
    if (pos < CAP) bucket[r * CAP + pos] = ecol[e];
}

// ---- fp32 GEMM: h = x@W + b. 512 thr, 256x128 tile, 8x8/thread. -------------
// launch_bounds(512,2): VGPR cap >=128 either semantics (working set ~114, NO spill).
// sW 64KB -> 2 blocks/CU -> 4 waves/SIMD.
__global__ __launch_bounds__(512, 2) void gemm_h(const float* __restrict__ A,
                                                 const float* __restrict__ W,
                                                 const float* __restrict__ b,
                                                 float* __restrict__ h) {
    __shared__ float sW[128 * 128];   // 64 KB
    const int tid = threadIdx.x;
    const int base = blockIdx.x * 256;

    // stage W (128x128): 512 threads x 8 float4
    #pragma unroll
    for (int i = 0; i < 8; ++i) {
        int idx = tid + i * 512;
        int r = idx >> 5, c4 = idx & 31;
        *(float4*)&sW[r * 128 + c4 * 4] = *(const float4*)(W + r * F + c4 * 4);
    }
    __syncthreads();

    const int tc = tid & 15;   // cols tc*8 .. tc*8+7
    const int tr = tid >> 4;   // 0..31: rows tr + 32*i, i=0..7

    const float* arow[8];
    #pragma unroll
    for (int i = 0; i < 8; ++i) {
        int row = base + tr + 32 * i;
        int rowc = row < NN ? row : NN - 1;   // clamp; store masked
        arow[i] = A + (size_t)rowc * F;
    }

    float acc[8][8];
    #pragma unroll
    for (int i = 0; i < 8; ++i)
        #pragma unroll
        for (int j = 0; j < 8; ++j) acc[i][j] = 0.f;

    for (int k4 = 0; k4 < 32; ++k4) {
        float4 a4[8];
        #pragma unroll
        for (int i = 0; i < 8; ++i)
            a4[i] = *(const float4*)(arow[i] + k4 * 4);   // 8 loads in flight
        #pragma unroll
        for (int kk = 0; kk < 4; ++kk) {
            int k = k4 * 4 + kk;
            float4 w0 = *(const float4*)&sW[k * 128 + tc * 8];
            float4 w1 = *(const float4*)&sW[k * 128 + tc * 8 + 4];
            float w[8] = {w0.x, w0.y, w0.z, w0.w, w1.x, w1.y, w1.z, w1.w};
            #pragma unroll
            for (int i = 0; i < 8; ++i) {
                const float* ap = (const float*)&a4[i];   // kk unrolled: static idx
                float av = ap[kk];
                #pragma unroll
                for (int j = 0; j < 8; ++j)
                    acc[i][j] = fmaf(av, w[j], acc[i][j]);
            }
        }
    }

    // epilogue: + bias, store h (norm happens after aggregation)
    float4 b0 = *(const float4*)(b + tc * 8);
    float4 b1 = *(const float4*)(b + tc * 8 + 4);
    float bb[8] = {b0.x, b0.y, b0.z, b0.w, b1.x, b1.y, b1.z, b1.w};
    #pragma unroll
    for (int i = 0; i < 8; ++i) {
        int row = base + tr + 32 * i;
        if (row < NN) {
            float4 o0 = make_float4(acc[i][0] + bb[0], acc[i][1] + bb[1],
                                    acc[i][2] + bb[2], acc[i][3] + bb[3]);
            float4 o1 = make_float4(acc[i][4] + bb[4], acc[i][5] + bb[5],
                                    acc[i][6] + bb[6], acc[i][7] + bb[7]);
            *(float4*)(h + (size_t)row * F + tc * 8) = o0;
            *(float4*)(h + (size_t)row * F + tc * 8 + 4) = o1;
        }
    }
}

// ------ mean aggregation over h + fused deg-divide + L2-normalize ------------
// 32 lanes per node, float4 gathers; deg==0 rows come out exactly 0.
__global__ __launch_bounds__(256) void agg_k(const float* __restrict__ h,
                                             const int* __restrict__ cnt,
                                             const int* __restrict__ bucket,
                                             float* __restrict__ out) {
    const int grp  = threadIdx.x >> 5;
    const int node = blockIdx.x * 8 + grp;
    const int gl   = threadIdx.x & 31;
    if (node >= NN) return;
    const int c = cnt[node];
    const int m = c < CAP ? c : CAP;
    const int idx0 = (gl < m)      ? bucket[node * CAP + gl]      : 0;
    const int idx1 = (32 + gl < m) ? bucket[node * CAP + 32 + gl] : 0;

    float sx = 0.f, sy = 0.f, sz = 0.f, sw = 0.f;
    int k = 0;
    for (; k + 4 <= m; k += 4) {
        int i0 = __shfl((k + 0) < 32 ? idx0 : idx1, (k + 0) & 31, 32);
        int i1 = __shfl((k + 1) < 32 ? idx0 : idx1, (k + 1) & 31, 32);
        int i2 = __shfl((k + 2) < 32 ? idx0 : idx1, (k + 2) & 31, 32);
        int i3 = __shfl((k + 3) < 32 ? idx0 : idx1, (k + 3) & 31, 32);
        float4 v0 = *(const float4*)(h + (size_t)i0 * F + gl * 4);
        float4 v1 = *(const float4*)(h + (size_t)i1 * F + gl * 4);
        float4 v2 = *(const float4*)(h + (size_t)i2 * F + gl * 4);
        float4 v3 = *(const float4*)(h + (size_t)i3 * F + gl * 4);
        sx += v0.x + v1.x + v2.x + v3.x;
        sy += v0.y + v1.y + v2.y + v3.y;
        sz += v0.z + v1.z + v2.z + v3.z;
        sw += v0.w + v1.w + v2.w + v3.w;
    }
    for (; k < m; ++k) {
        int ii = __shfl(k < 32 ? idx0 : idx1, k & 31, 32);
        float4 v = *(const float4*)(h + (size_t)ii * F + gl * 4);
        sx += v.x; sy += v.y; sz += v.z; sw += v.w;
    }
    const float inv = 1.f / (float)(c > 1 ? c : 1);
    float vx = sx * inv, vy = sy * inv, vz = sz * inv, vw = sw * inv;

    float sumsq = vx * vx + vy * vy + vz * vz + vw * vw;
    #pragma unroll
    for (int off = 1; off < 32; off <<= 1)
        sumsq += __shfl_xor(sumsq, off, 32);
    float s = 1.f / fmaxf(sqrtf(sumsq), 1e-12f);

    float4 r;
    r.x = vx * s; r.y = vy * s; r.z = vz * s; r.w = vw * s;
    *(float4*)(out + (size_t)node * F + gl * 4) = r;
}

extern "C" void kernel_launch(void* const* d_in, const int* in_sizes, int n_in,
                              void* d_out, int out_size, void* d_ws, size_t ws_size,
                              hipStream_t stream) {
    const float* x    = (const float*)d_in[0];
    const int*   erow = (const int*)d_in[1];
    const int*   ecol = (const int*)d_in[2];
    const float* W    = (const float*)d_in[3];
    const float* b    = (const float*)d_in[4];
    float* out = (float*)d_out;

    // workspace layout: h [NN*F f32] | cnt [NN i32] | bucket [NN*CAP i32]
    float* h      = (float*)d_ws;
    int*   cnt    = (int*)(h + (size_t)NN * F);
    int*   bucket = cnt + NN;

    hipMemsetAsync(cnt, 0, NN * sizeof(int), stream);
    build_k<<<(NE + 255) / 256, 256, 0, stream>>>(erow, ecol, cnt, bucket);
    gemm_h<<<(NN + 255) / 256, 512, 0, stream>>>(x, W, b, h);
    agg_k<<<(NN + 7) / 8, 256, 0, stream>>>(h, cnt, bucket, out);
}

// Round 12
// 344.504 us; speedup vs baseline: 1.3493x; 1.1091x over previous
//
#include <hip/hip_runtime.h>

#define NN 100000
#define NE 1600000
#define F 128
#define CAP 64
#define SLICES 8
#define RPS ((NN + SLICES - 1) / SLICES)   // 12500 rows per slice
#define CHUNKS 120

// ---- build v2: XCD-sliced inverted adjacency -------------------------------
// block b: slice = b&7 (round-robin XCD heuristic -> slice-local L2 writes),
// chunk = b>>3 scans 1/CHUNKS of the edges. Exact regardless of XCD mapping.
__global__ __launch_bounds__(256) void build_k(const int* __restrict__ erow,
                                               const int* __restrict__ ecol,
                                               int* __restrict__ cnt,
                                               int* __restrict__ bucket) {
    const int slice = blockIdx.x & (SLICES - 1);
    const int chunk = blockIdx.x >> 3;
    const int lo = slice * RPS, hi = lo + RPS;
    const int stride = CHUNKS * 256;
    for (int e = chunk * 256 + threadIdx.x; e < NE; e += stride) {
        int r = erow[e];
        if (r >= lo && r < hi) {
            int pos = atomicAdd(&cnt[r], 1);
            if (pos < CAP) bucket[r * CAP + pos] = ecol[e];
        }
    }
}

// ---- fp32 GEMM: h = x@W + b. 512 thr, 256x128 tile, 8x8/thread. -------------
// v2: a4 prefetch split into 2 groups of 4 rows -> peak regs ~112 (< 128 cap,
// no spill under either launch_bounds semantics). sW re-read per half
// (16 ds_read_b128/thread/k4; LDS pipe ~40% of VALU -> not critical).
__global__ __launch_bounds__(512, 2) void gemm_h(const float* __restrict__ A,
                                                 const float* __restrict__ W,
                                                 const float* __restrict__ b,
                                                 float* __restrict__ h) {
    __shared__ float sW[128 * 128];   // 64 KB -> 2 blocks/CU
    const int tid = threadIdx.x;
    const int base = blockIdx.x * 256;

    #pragma unroll
    for (int i = 0; i < 8; ++i) {
        int idx = tid + i * 512;
        int r = idx >> 5, c4 = idx & 31;
        *(float4*)&sW[r * 128 + c4 * 4] = *(const float4*)(W + r * F + c4 * 4);
    }
    __syncthreads();

    const int tc = tid & 15;   // cols tc*8 .. tc*8+7
    const int tr = tid >> 4;   // 0..31: rows tr + 32*i, i=0..7

    const float* arow[8];
    #pragma unroll
    for (int i = 0; i < 8; ++i) {
        int row = base + tr + 32 * i;
        int rowc = row < NN ? row : NN - 1;   // clamp; store masked
        arow[i] = A + (size_t)rowc * F;
    }

    float acc[8][8];
    #pragma unroll
    for (int i = 0; i < 8; ++i)
        #pragma unroll
        for (int j = 0; j < 8; ++j) acc[i][j] = 0.f;

    for (int k4 = 0; k4 < 32; ++k4) {
        #pragma unroll
        for (int half = 0; half < 2; ++half) {
            float4 a4[4];
            #pragma unroll
            for (int i = 0; i < 4; ++i)
                a4[i] = *(const float4*)(arow[half * 4 + i] + k4 * 4);
            #pragma unroll
            for (int kk = 0; kk < 4; ++kk) {
                int k = k4 * 4 + kk;
                float4 w0 = *(const float4*)&sW[k * 128 + tc * 8];
                float4 w1 = *(const float4*)&sW[k * 128 + tc * 8 + 4];
                float w[8] = {w0.x, w0.y, w0.z, w0.w, w1.x, w1.y, w1.z, w1.w};
                #pragma unroll
                for (int i = 0; i < 4; ++i) {
                    const float* ap = (const float*)&a4[i];   // static idx (unrolled)
                    float av = ap[kk];
                    #pragma unroll
                    for (int j = 0; j < 8; ++j)
                        acc[half * 4 + i][j] = fmaf(av, w[j], acc[half * 4 + i][j]);
                }
            }
        }
    }

    // epilogue: + bias, store h (norm happens after aggregation)
    float4 b0 = *(const float4*)(b + tc * 8);
    float4 b1 = *(const float4*)(b + tc * 8 + 4);
    float bb[8] = {b0.x, b0.y, b0.z, b0.w, b1.x, b1.y, b1.z, b1.w};
    #pragma unroll
    for (int i = 0; i < 8; ++i) {
        int row = base + tr + 32 * i;
        if (row < NN) {
            float4 o0 = make_float4(acc[i][0] + bb[0], acc[i][1] + bb[1],
                                    acc[i][2] + bb[2], acc[i][3] + bb[3]);
            float4 o1 = make_float4(acc[i][4] + bb[4], acc[i][5] + bb[5],
                                    acc[i][6] + bb[6], acc[i][7] + bb[7]);
            *(float4*)(h + (size_t)row * F + tc * 8) = o0;
            *(float4*)(h + (size_t)row * F + tc * 8 + 4) = o1;
        }
    }
}

// ------ mean aggregation over h + fused deg-divide + L2-normalize ------------
__global__ __launch_bounds__(256) void agg_k(const float* __restrict__ h,
                                             const int* __restrict__ cnt,
                                             const int* __restrict__ bucket,
                                             float* __restrict__ out) {
    const int grp  = threadIdx.x >> 5;
    const int node = blockIdx.x * 8 + grp;
    const int gl   = threadIdx.x & 31;
    if (node >= NN) return;
    const int c = cnt[node];
    const int m = c < CAP ? c : CAP;
    const int idx0 = (gl < m)      ? bucket[node * CAP + gl]      : 0;
    const int idx1 = (32 + gl < m) ? bucket[node * CAP + 32 + gl] : 0;

    float sx = 0.f, sy = 0.f, sz = 0.f, sw = 0.f;
    int k = 0;
    for (; k + 4 <= m; k += 4) {
        int i0 = __shfl((k + 0) < 32 ? idx0 : idx1, (k + 0) & 31, 32);
        int i1 = __shfl((k + 1) < 32 ? idx0 : idx1, (k + 1) & 31, 32);
        int i2 = __shfl((k + 2) < 32 ? idx0 : idx1, (k + 2) & 31, 32);
        int i3 = __shfl((k + 3) < 32 ? idx0 : idx1, (k + 3) & 31, 32);
        float4 v0 = *(const float4*)(h + (size_t)i0 * F + gl * 4);
        float4 v1 = *(const float4*)(h + (size_t)i1 * F + gl * 4);
        float4 v2 = *(const float4*)(h + (size_t)i2 * F + gl * 4);
        float4 v3 = *(const float4*)(h + (size_t)i3 * F + gl * 4);
        sx += v0.x + v1.x + v2.x + v3.x;
        sy += v0.y + v1.y + v2.y + v3.y;
        sz += v0.z + v1.z + v2.z + v3.z;
        sw += v0.w + v1.w + v2.w + v3.w;
    }
    for (; k < m; ++k) {
        int ii = __shfl(k < 32 ? idx0 : idx1, k & 31, 32);
        float4 v = *(const float4*)(h + (size_t)ii * F + gl * 4);
        sx += v.x; sy += v.y; sz += v.z; sw += v.w;
    }
    const float inv = 1.f / (float)(c > 1 ? c : 1);
    float vx = sx * inv, vy = sy * inv, vz = sz * inv, vw = sw * inv;

    float sumsq = vx * vx + vy * vy + vz * vz + vw * vw;
    #pragma unroll
    for (int off = 1; off < 32; off <<= 1)
        sumsq += __shfl_xor(sumsq, off, 32);
    float s = 1.f / fmaxf(sqrtf(sumsq), 1e-12f);

    float4 r;
    r.x = vx * s; r.y = vy * s; r.z = vz * s; r.w = vw * s;
    *(float4*)(out + (size_t)node * F + gl * 4) = r;
}

extern "C" void kernel_launch(void* const* d_in, const int* in_sizes, int n_in,
                              void* d_out, int out_size, void* d_ws, size_t ws_size,
                              hipStream_t stream) {
    const float* x    = (const float*)d_in[0];
    const int*   erow = (const int*)d_in[1];
    const int*   ecol = (const int*)d_in[2];
    const float* W    = (const float*)d_in[3];
    const float* b    = (const float*)d_in[4];
    float* out = (float*)d_out;

    // workspace layout: h [NN*F f32] | cnt [NN i32] | bucket [NN*CAP i32]
    float* h      = (float*)d_ws;
    int*   cnt    = (int*)(h + (size_t)NN * F);
    int*   bucket = cnt + NN;

    hipMemsetAsync(cnt, 0, NN * sizeof(int), stream);
    build_k<<<SLICES * CHUNKS, 256, 0, stream>>>(erow, ecol, cnt, bucket);
    gemm_h<<<(NN + 255) / 256, 512, 0, stream>>>(x, W, b, h);
    agg_k<<<(NN + 7) / 8, 256, 0, stream>>>(h, cnt, bucket, out);
}

// Round 16
// 287.221 us; speedup vs baseline: 1.6184x; 1.1994x over previous
//
#include <hip/hip_runtime.h>

#define NN 100000
#define NE 1600000
#define F 128
#define CAP 64
#define SLICES 8
#define RPS ((NN + SLICES - 1) / SLICES)   // 12500 rows per slice
#define CHUNKS 120

// ---- build v2: XCD-sliced inverted adjacency -------------------------------
__global__ __launch_bounds__(256) void build_k(const int* __restrict__ erow,
                                               const int* __restrict__ ecol,
                                               int* __restrict__ cnt,
                                               int* __restrict__ bucket) {
    const int slice = blockIdx.x & (SLICES - 1);
    const int chunk = blockIdx.x >> 3;
    const int lo = slice * RPS, hi = lo + RPS;
    const int stride = CHUNKS * 256;
    for (int e = chunk * 256 + threadIdx.x; e < NE; e += stride) {
        int r = erow[e];
        if (r >= lo && r < hi) {
            int pos = atomicAdd(&cnt[r], 1);
            if (pos < CAP) bucket[r * CAP + pos] = ecol[e];
        }
    }
}

__device__ __forceinline__ unsigned short f2bf(float x) {   // RNE
    unsigned u = __float_as_uint(x);
    unsigned r = (u + 0x7fffu + ((u >> 16) & 1u)) >> 16;
    return (unsigned short)r;
}

// ---- fp32 GEMM: h = x@W + b, h stored BF16. 512 thr, 256x128 tile. ----------
__global__ __launch_bounds__(512, 2) void gemm_h(const float* __restrict__ A,
                                                 const float* __restrict__ W,
                                                 const float* __restrict__ b,
                                                 unsigned short* __restrict__ h) {
    __shared__ float sW[128 * 128];   // 64 KB -> 2 blocks/CU
    const int tid = threadIdx.x;
    const int base = blockIdx.x * 256;

    #pragma unroll
    for (int i = 0; i < 8; ++i) {
        int idx = tid + i * 512;
        int r = idx >> 5, c4 = idx & 31;
        *(float4*)&sW[r * 128 + c4 * 4] = *(const float4*)(W + r * F + c4 * 4);
    }
    __syncthreads();

    const int tc = tid & 15;   // cols tc*8 .. tc*8+7  (16 x 8 = 128 per row)
    const int tr = tid >> 4;   // 0..31: rows tr + 32*i, i=0..7

    const float* arow[8];
    #pragma unroll
    for (int i = 0; i < 8; ++i) {
        int row = base + tr + 32 * i;
        int rowc = row < NN ? row : NN - 1;   // clamp; store masked
        arow[i] = A + (size_t)rowc * F;
    }

    float acc[8][8];
    #pragma unroll
    for (int i = 0; i < 8; ++i)
        #pragma unroll
        for (int j = 0; j < 8; ++j) acc[i][j] = 0.f;

    for (int k4 = 0; k4 < 32; ++k4) {
        #pragma unroll
        for (int half = 0; half < 2; ++half) {
            float4 a4[4];
            #pragma unroll
            for (int i = 0; i < 4; ++i)
                a4[i] = *(const float4*)(arow[half * 4 + i] + k4 * 4);
            #pragma unroll
            for (int kk = 0; kk < 4; ++kk) {
                int k = k4 * 4 + kk;
                float4 w0 = *(const float4*)&sW[k * 128 + tc * 8];
                float4 w1 = *(const float4*)&sW[k * 128 + tc * 8 + 4];
                float w[8] = {w0.x, w0.y, w0.z, w0.w, w1.x, w1.y, w1.z, w1.w};
                #pragma unroll
                for (int i = 0; i < 4; ++i) {
                    const float* ap = (const float*)&a4[i];
                    float av = ap[kk];
                    #pragma unroll
                    for (int j = 0; j < 8; ++j)
                        acc[half * 4 + i][j] = fmaf(av, w[j], acc[half * 4 + i][j]);
                }
            }
        }
    }

    // epilogue: + bias, pack bf16 (RNE), 16 B per row-chunk
    float4 b0 = *(const float4*)(b + tc * 8);
    float4 b1 = *(const float4*)(b + tc * 8 + 4);
    float bb[8] = {b0.x, b0.y, b0.z, b0.w, b1.x, b1.y, b1.z, b1.w};
    #pragma unroll
    for (int i = 0; i < 8; ++i) {
        int row = base + tr + 32 * i;
        if (row < NN) {
            uint4 p;
            float o[8];
            #pragma unroll
            for (int j = 0; j < 8; ++j) o[j] = acc[i][j] + bb[j];
            p.x = (unsigned)f2bf(o[0]) | ((unsigned)f2bf(o[1]) << 16);
            p.y = (unsigned)f2bf(o[2]) | ((unsigned)f2bf(o[3]) << 16);
            p.z = (unsigned)f2bf(o[4]) | ((unsigned)f2bf(o[5]) << 16);
            p.w = (unsigned)f2bf(o[6]) | ((unsigned)f2bf(o[7]) << 16);
            *(uint4*)(h + (size_t)row * F + tc * 8) = p;
        }
    }
}

// ------ mean aggregation over bf16 h + deg-divide + L2-normalize -------------
// 32 lanes/node = 2 neighbors x 16 chunk-owners. One uint4 (8 bf16) per lane;
// 16 lanes x 8 = one full 256-B row per neighbor. fp32 accumulate, fp32 out.
__global__ __launch_bounds__(256) void agg_k(const unsigned short* __restrict__ h,
                                             const int* __restrict__ cnt,
                                             const int* __restrict__ bucket,
                                             float* __restrict__ out) {
    const int grp  = threadIdx.x >> 5;
    const int node = blockIdx.x * 8 + grp;
    const int gl   = threadIdx.x & 31;
    if (node >= NN) return;
    const int half = gl >> 4;     // which neighbor of the current pair
    const int hl   = gl & 15;     // owns bf16 elements [hl*8, hl*8+8)
    const int c = cnt[node];
    const int m = c < CAP ? c : CAP;
    const int idx0 = (gl < m)      ? bucket[node * CAP + gl]      : 0;
    const int idx1 = (32 + gl < m) ? bucket[node * CAP + 32 + gl] : 0;

    float s[8];
    #pragma unroll
    for (int j = 0; j < 8; ++j) s[j] = 0.f;

    int k = 0;
    for (; k + 2 <= m; k += 2) {
        int ia = __shfl(k < 32 ? idx0 : idx1, k & 31, 32);         // k uniform
        int ib = __shfl((k + 1) < 32 ? idx0 : idx1, (k + 1) & 31, 32);
        int ii = half ? ib : ia;
        uint4 v = *(const uint4*)(h + (size_t)ii * F + hl * 8);
        const unsigned* u = (const unsigned*)&v;
        #pragma unroll
        for (int j = 0; j < 4; ++j) {
            s[2 * j]     += __uint_as_float(u[j] << 16);
            s[2 * j + 1] += __uint_as_float(u[j] & 0xffff0000u);
        }
    }
    if (k < m) {   // odd tail: half 0 covers the full row alone
        int ia = __shfl(k < 32 ? idx0 : idx1, k & 31, 32);
        if (half == 0) {
            uint4 v = *(const uint4*)(h + (size_t)ia * F + hl * 8);
            const unsigned* u = (const unsigned*)&v;
            #pragma unroll
            for (int j = 0; j < 4; ++j) {
                s[2 * j]     += __uint_as_float(u[j] << 16);
                s[2 * j + 1] += __uint_as_float(u[j] & 0xffff0000u);
            }
        }
    }

    // merge the two neighbor-halves (lane gl <-> gl^16 share chunk hl)
    #pragma unroll
    for (int j = 0; j < 8; ++j) s[j] += __shfl_xor(s[j], 16, 32);

    const float inv = 1.f / (float)(c > 1 ? c : 1);
    float v[8];
    float sumsq = 0.f;
    #pragma unroll
    for (int j = 0; j < 8; ++j) { v[j] = s[j] * inv; sumsq += v[j] * v[j]; }
    #pragma unroll
    for (int off = 1; off < 16; off <<= 1)      // reduce across the 16 chunk-owners
        sumsq += __shfl_xor(sumsq, off, 32);
    float sc = 1.f / fmaxf(sqrtf(sumsq), 1e-12f);

    // halves write disjoint float4 quarters -> contiguous 512 B per row
    float4 o = half ? make_float4(v[4] * sc, v[5] * sc, v[6] * sc, v[7] * sc)
                    : make_float4(v[0] * sc, v[1] * sc, v[2] * sc, v[3] * sc);
    *(float4*)(out + (size_t)node * F + hl * 8 + half * 4) = o;
}

extern "C" void kernel_launch(void* const* d_in, const int* in_sizes, int n_in,
                              void* d_out, int out_size, void* d_ws, size_t ws_size,
                              hipStream_t stream) {
    const float* x    = (const float*)d_in[0];
    const int*   erow = (const int*)d_in[1];
    const int*   ecol = (const int*)d_in[2];
    const float* W    = (const float*)d_in[3];
    const float* b    = (const float*)d_in[4];
    float* out = (float*)d_out;

    // workspace: h bf16 [NN*F] | cnt [NN i32] | bucket [NN*CAP i32]
    unsigned short* h = (unsigned short*)d_ws;
    int* cnt    = (int*)(h + (size_t)NN * F);
    int* bucket = cnt + NN;

    hipMemsetAsync(cnt, 0, NN * sizeof(int), stream);
    build_k<<<SLICES * CHUNKS, 256, 0, stream>>>(erow, ecol, cnt, bucket);
    gemm_h<<<(NN + 255) / 256, 512, 0, stream>>>(x, W, b, h);
    agg_k<<<(NN + 7) / 8, 256, 0, stream>>>(h, cnt, bucket, out);
}